// Round 7
// baseline (20.623 us; speedup 1.0000x reference)
//
#include <hip/hip_runtime.h>

constexpr int BLK = 256;
constexpr int P   = 2;     // adjacent points per thread (one packed pair)

typedef float v2f __attribute__((ext_vector_type(2)));

__device__ __forceinline__ v2f splat(float s) { return (v2f){s, s}; }
__device__ __forceinline__ v2f pk_fma(v2f a, v2f b, v2f c) {
    return __builtin_elementwise_fma(a, b, c);
}
__device__ __forceinline__ v2f pk_max0(v2f a) {
    return __builtin_elementwise_max(a, (v2f){0.0f, 0.0f});
}
__device__ __forceinline__ v2f pk_min0(v2f a) {
    return __builtin_elementwise_min(a, (v2f){0.0f, 0.0f});
}
__device__ __forceinline__ v2f pk_clamp(v2f a, float lo, float hi) {
    return __builtin_elementwise_min(__builtin_elementwise_max(a, splat(lo)), splat(hi));
}

// ---------- native transcendentals ----------
__device__ __forceinline__ float fast_rcp(float x) { return __builtin_amdgcn_rcpf(x); }

__device__ __forceinline__ float fast_exp2(float x) {
#if __has_builtin(__builtin_amdgcn_exp2f)
    return __builtin_amdgcn_exp2f(x);
#else
    return __expf(x * 0.6931471805599453f);
#endif
}
__device__ __forceinline__ float fast_log2(float x) {
#if __has_builtin(__builtin_amdgcn_logf)
    return __builtin_amdgcn_logf(x);
#else
    return __log2f(x);
#endif
}

#define LOG2E 1.4426950408889634f
#define LN2   0.6931471805599453f

__device__ __forceinline__ v2f pk_exp2(v2f t) { return (v2f){fast_exp2(t.x), fast_exp2(t.y)}; }
__device__ __forceinline__ v2f pk_rcp(v2f t)  { return (v2f){fast_rcp(t.x),  fast_rcp(t.y)};  }
// one hardware rcp for both components: rcp(a.x), rcp(a.y) via rcp(a.x*a.y)
__device__ __forceinline__ v2f pk_rcp_paired(v2f d) {
    float r = fast_rcp(d.x * d.y);
    return (v2f){r * d.y, r * d.x};
}

// ---------- activations on a packed pair ----------
template<int A> __device__ __forceinline__ v2f act2(v2f z);
// 0: relu
template<> __device__ __forceinline__ v2f act2<0>(v2f z) { return pk_max0(z); }
// 1: tanh — depth-7 continued-fraction Pade, clamp +-4.5, single paired rcp.
//    |err| < 5e-5 on [-4.5,4.5], <= 2.1e-4 beyond (saturation).
template<> __device__ __forceinline__ v2f act2<1>(v2f z) {
    v2f xc = pk_clamp(z, -4.5f, 4.5f);
    v2f u  = xc * xc;
    v2f n  = pk_fma(pk_fma(u + 378.0f, u, splat(17325.0f)), u, splat(135135.0f)) * xc;
    v2f d  = pk_fma(pk_fma(pk_fma(u, splat(28.0f), splat(3150.0f)), u, splat(62370.0f)),
                    u, splat(135135.0f));
    return n * pk_rcp_paired(d);
}
// 2: elu = max(z,0) + min(e^z - 1, 0)   (branch-free, inf-safe)
template<> __device__ __forceinline__ v2f act2<2>(v2f z) {
    v2f em = pk_exp2(z * LOG2E) - 1.0f;
    return pk_max0(z) + pk_min0(em);
}
// 3: silu = z * rcp(1+2^{-log2e*z})
template<> __device__ __forceinline__ v2f act2<3>(v2f z) {
    v2f e = pk_exp2(z * (-LOG2E));
    return z * pk_rcp(e + 1.0f);
}
// 4: gelu ~= z * sigmoid(1.702 z)
template<> __device__ __forceinline__ v2f act2<4>(v2f z) {
    v2f e = pk_exp2(z * (-1.702f * LOG2E));
    return z * pk_rcp(e + 1.0f);
}
// 5: none
template<> __device__ __forceinline__ v2f act2<5>(v2f z) { return z; }
// 6: selu = sc*max(z,0) + min(sc*al*(e^z-1), 0)   (branch-free, inf-safe)
template<> __device__ __forceinline__ v2f act2<6>(v2f z) {
    const float sc   = 1.0507009873554805f;
    const float scal = 1.7580993408473766f;   // sc*alpha
    v2f e = pk_exp2(z * LOG2E);
    v2f n = pk_fma(splat(scal), e, splat(-scal));
    return pk_fma(pk_max0(z), splat(sc), pk_min0(n));
}
// 7: softplus = max(z,0) + ln2*log2(1+2^{-log2e*|z|})
template<> __device__ __forceinline__ v2f act2<7>(v2f z) {
    v2f a = __builtin_elementwise_abs(z) * (-LOG2E);
    v2f d = pk_exp2(a) + 1.0f;
    v2f l = (v2f){fast_log2(d.x), fast_log2(d.y)};
    return pk_fma(splat(LN2), l, pk_max0(z));
}

// ---------- one expert, compile-time index A -> all weight reads uniform (s_load) ----------
template<int A>
__device__ __forceinline__ void run_expert(const float* __restrict__ W1,
                                           const float* __restrict__ b1,
                                           const float* __restrict__ W2,
                                           const float* __restrict__ ew,
                                           v2f re, v2f im, v2f am, v2f& acc) {
    v2f accE = (v2f){0.0f, 0.0f};
#pragma unroll
    for (int h = 0; h < 16; ++h) {
        const float wre = W1[A * 48 + h];        // W1: (8,3,16)
        const float wim = W1[A * 48 + 16 + h];
        const float wam = W1[A * 48 + 32 + h];
        const float bb  = b1[A * 16 + h];
        const float w2  = W2[A * 16 + h];
        v2f z = pk_fma(re, splat(wre),
                pk_fma(im, splat(wim),
                pk_fma(am, splat(wam), splat(bb))));
        accE = pk_fma(act2<A>(z), splat(w2), accE);
    }
    acc = pk_fma(accE, splat(ew[A]), acc);
    __builtin_amdgcn_sched_barrier(0);   // bound the scheduling window per expert
}

__global__ __launch_bounds__(BLK, 4)
void moe_kernel(const float* __restrict__ x,
                const float* __restrict__ W1,
                const float* __restrict__ b1,
                const float* __restrict__ W2,
                const float* __restrict__ b2,
                const float* __restrict__ ew,
                float* __restrict__ out, int npts) {
    const int pr = blockIdx.x * BLK + threadIdx.x;   // pair index
    if (pr * P >= npts) return;

    float bconst = 0.0f;
#pragma unroll
    for (int i = 0; i < 8; ++i) bconst = fmaf(ew[i], b2[i], bconst);

    // two adjacent points: one float4 load (16B/lane, coalesced)
    float4 v = reinterpret_cast<const float4*>(x)[pr];
    v2f re = (v2f){v.x, v.z};
    v2f im = (v2f){v.y, v.w};
    v2f r2 = pk_fma(re, re, im * im);
    v2f am = (v2f){__builtin_amdgcn_sqrtf(r2.x), __builtin_amdgcn_sqrtf(r2.y)};

    // analytic experts + folded b2 bias; sin/cos via raw v_sin/v_cos (arg in revolutions)
    const float INV2PI = 0.15915494309189535f;
    v2f s = am * INV2PI;
    v2f sn = (v2f){__builtin_amdgcn_sinf(s.x), __builtin_amdgcn_sinf(s.y)};
    v2f cs = (v2f){__builtin_amdgcn_cosf(s.x), __builtin_amdgcn_cosf(s.y)};

    v2f acc = pk_fma(splat(ew[8]),
                     __builtin_elementwise_abs(re) + __builtin_elementwise_abs(im),
                     splat(bconst));                              // 'abs'
    acc = pk_fma(splat(ew[9]), am, acc);                          // 'modulus'
    acc = pk_fma(splat(ew[10]), sn, acc);                         // 'sin'
    acc = pk_fma(splat(ew[11]), cs, acc);                         // 'cos'

    run_expert<0>(W1, b1, W2, ew, re, im, am, acc);  // relu
    run_expert<1>(W1, b1, W2, ew, re, im, am, acc);  // tanh (Pade)
    run_expert<2>(W1, b1, W2, ew, re, im, am, acc);  // elu
    run_expert<3>(W1, b1, W2, ew, re, im, am, acc);  // silu
    run_expert<4>(W1, b1, W2, ew, re, im, am, acc);  // gelu (sigmoid form)
    run_expert<5>(W1, b1, W2, ew, re, im, am, acc);  // none
    run_expert<6>(W1, b1, W2, ew, re, im, am, acc);  // selu
    run_expert<7>(W1, b1, W2, ew, re, im, am, acc);  // softplus

    reinterpret_cast<float2*>(out)[pr] = make_float2(acc.x, acc.y);
}

extern "C" void kernel_launch(void* const* d_in, const int* in_sizes, int n_in,
                              void* d_out, int out_size, void* d_ws, size_t ws_size,
                              hipStream_t stream) {
    const float* x  = (const float*)d_in[0];
    const float* W1 = (const float*)d_in[1];
    const float* b1 = (const float*)d_in[2];
    const float* W2 = (const float*)d_in[3];
    const float* b2 = (const float*)d_in[4];
    const float* ew = (const float*)d_in[5];
    float* out = (float*)d_out;

    const int npts = in_sizes[0] / 2;  // (B,S,C,2) -> B*S*C points
    const int blocks = (npts + BLK * P - 1) / (BLK * P);
    hipLaunchKernelGGL(moe_kernel, dim3(blocks), dim3(BLK), 0, stream,
                       x, W1, b1, W2, b2, ew, out, npts);
}